// Round 1
// baseline (288.809 us; speedup 1.0000x reference)
//
#include <hip/hip_runtime.h>

#define HW    262144      // 512*512
#define BNUM  4
#define NC    33          // labels 0..32
#define NI    32          // instance channels
#define NBINS 4096
#define BINW  (2.0f / NBINS)
#define SCALE (NBINS / 2.0f)   // 2048

// word (float) offsets within each sample's workspace slice
#define W_HPOS 0
#define W_HNEG 4096
#define W_HSUM 8192
#define W_E0   12288
#define W_E1   (W_E0 + NC)
#define W_SS   (W_E1 + NC)
#define W_CNT  (W_SS + NC)
#define W_SVAR (W_CNT + NC)
#define W_SIG  (W_SVAR + 1)
#define W_Q    (W_SIG + NC)
#define W_C0   (W_Q + NC)
#define W_C1   (W_C0 + NC)
#define W_LOSS (W_C1 + NC)
#define W_STRIDE 12608     // > 12554, 32-aligned

// ---------------- Pass A: per-instance stats (counts, emb sums, sigma sums)
__global__ void __launch_bounds__(256) stats_kernel(
    const float* __restrict__ emb, const float* __restrict__ sig,
    const int* __restrict__ gt, float* __restrict__ ws) {
  int s = blockIdx.y;
  float* wsS = ws + (size_t)s * W_STRIDE;
  __shared__ float a0[NC], a1[NC], as_[NC];
  __shared__ unsigned ac[NC];
  int t = threadIdx.x;
  if (t < NC) { a0[t] = 0.f; a1[t] = 0.f; as_[t] = 0.f; ac[t] = 0u; }
  __syncthreads();
  const float* e0p = emb + (size_t)s * 2 * HW;
  const float* e1p = e0p + HW;
  const float* sp  = sig + (size_t)s * HW;
  const int*   gp  = gt  + (size_t)s * HW;
  int base = blockIdx.x * 1024;
  for (int i = 0; i < 4; ++i) {
    int idx = base + i * 256 + t;
    int lab = gp[idx];
    if (lab > 0) {
      atomicAdd(&a0[lab], e0p[idx]);
      atomicAdd(&a1[lab], e1p[idx]);
      atomicAdd(&as_[lab], sp[idx]);
      atomicAdd(&ac[lab], 1u);
    }
  }
  __syncthreads();
  if (t >= 1 && t < NC && ac[t]) {
    atomicAdd(&wsS[W_E0 + t], a0[t]);
    atomicAdd(&wsS[W_E1 + t], a1[t]);
    atomicAdd(&wsS[W_SS + t], as_[t]);
    atomicAdd((unsigned*)wsS + (W_CNT + t), ac[t]);
  }
}

// ---------------- Prep: centers, sigma, q = -0.5/sigma^2
__global__ void prep_kernel(float* __restrict__ ws) {
  int s = blockIdx.x;
  float* wsS = ws + (size_t)s * W_STRIDE;
  const unsigned* wsu = (const unsigned*)wsS;
  int n = threadIdx.x;
  if (n >= 1 && n < NC) {
    float inv = 1.0f / (float)wsu[W_CNT + n];
    float sg = wsS[W_SS + n] * inv;
    wsS[W_SIG + n] = sg;
    wsS[W_Q + n]   = -0.5f / (sg * sg);
    wsS[W_C0 + n]  = wsS[W_E0 + n] * inv;
    wsS[W_C1 + n]  = wsS[W_E1 + n] * inv;
  }
}

// ---------------- Pass B: error histogram (pos cnt, neg cnt, sum of e per bin)
__global__ void __launch_bounds__(512) hist_kernel(
    const float* __restrict__ emb, const float* __restrict__ sig,
    const int* __restrict__ gt, float* __restrict__ ws) {
  int s = blockIdx.y;
  float* wsS = ws + (size_t)s * W_STRIDE;
  __shared__ unsigned hpos[NBINS], hneg[NBINS];
  __shared__ float hsum[NBINS];
  __shared__ float c0s[NC], c1s[NC], qs[NC], sgs[NC];
  __shared__ float vred[8];
  int t = threadIdx.x;
  for (int k = t; k < NBINS; k += 512) { hpos[k] = 0u; hneg[k] = 0u; hsum[k] = 0.f; }
  if (t < NC) {
    c0s[t] = wsS[W_C0 + t]; c1s[t] = wsS[W_C1 + t];
    qs[t]  = wsS[W_Q + t];  sgs[t] = wsS[W_SIG + t];
  }
  __syncthreads();
  const float* e0p = emb + (size_t)s * 2 * HW;
  const float* e1p = e0p + HW;
  const float* sp  = sig + (size_t)s * HW;
  const int*   gp  = gt  + (size_t)s * HW;
  int base = blockIdx.x * 4096;
  unsigned rneg0 = 0, rpos2 = 0;
  float vs = 0.f;
  for (int i = 0; i < 8; ++i) {
    int idx = base + i * 512 + t;
    int lab = gp[idx];
    float e0 = e0p[idx], e1 = e1p[idx];
    if (lab > 0) { float d = sp[idx] - sgs[lab]; vs += d * d; }
    #pragma unroll 4
    for (int n = 1; n <= NI; ++n) {
      float dx = c0s[n] - e0, dy = c1s[n] - e1;
      float pr = __expf((dx * dx + dy * dy) * qs[n]);
      if (lab == n) {
        float e = 2.0f - 2.0f * pr;
        if (e >= 2.0f) {
          rpos2++;                           // exact: e == 2, sum = 2*count
        } else {
          int b = (int)(e * SCALE);
          atomicAdd(&hpos[b], 1u);
          atomicAdd(&hsum[b], e);
        }
      } else {
        float e = 2.0f * pr;
        if (e < BINW) {
          rneg0++;                           // bin-0 negative; drop sum (err <= BINW)
        } else {
          int b = (int)(e * SCALE);
          if (b > NBINS - 1) b = NBINS - 1;  // e == 2.0 exactly (pr == 1)
          atomicAdd(&hneg[b], 1u);
          atomicAdd(&hsum[b], e);
        }
      }
    }
  }
  if (rneg0) atomicAdd(&hneg[0], rneg0);
  if (rpos2) {
    atomicAdd(&hpos[NBINS - 1], rpos2);
    atomicAdd(&hsum[NBINS - 1], 2.0f * (float)rpos2);
  }
  // reduce variance partial: wave shuffle then cross-wave via LDS
  for (int o = 32; o; o >>= 1) vs += __shfl_down(vs, o);
  if ((t & 63) == 0) vred[t >> 6] = vs;
  __syncthreads();
  if (t == 0) {
    float tot = 0.f;
    for (int i = 0; i < 8; ++i) tot += vred[i];
    atomicAdd(&wsS[W_SVAR], tot);
  }
  // flush LDS histogram to global (skip empty bins)
  unsigned* wsu = (unsigned*)wsS;
  for (int k = t; k < NBINS; k += 512) {
    unsigned p_ = hpos[k], n_ = hneg[k];
    float sm = hsum[k];
    if (p_) atomicAdd(&wsu[W_HPOS + k], p_);
    if (n_) atomicAdd(&wsu[W_HNEG + k], n_);
    if (sm != 0.f) atomicAdd(&wsS[W_HSUM + k], sm);
  }
}

// ---------------- Pass C: descending-bin scan -> Lovasz loss + variance term
__global__ void __launch_bounds__(256) scan_kernel(float* __restrict__ ws) {
  int s = blockIdx.x;
  float* wsS = ws + (size_t)s * W_STRIDE;
  const unsigned* wsu = (const unsigned*)wsS;
  __shared__ unsigned snp[256], snn[256];
  __shared__ unsigned tot[2];
  __shared__ float red[256];
  int t = threadIdx.x;
  const int CH = NBINS / 256;  // 16
  int j0 = t * CH;
  unsigned np = 0, nn = 0;
  for (int k = 0; k < CH; ++k) {
    int b = NBINS - 1 - (j0 + k);
    np += wsu[W_HPOS + b];
    nn += wsu[W_HNEG + b];
  }
  snp[t] = np; snn[t] = nn;
  __syncthreads();
  if (t == 0) {
    unsigned ap = 0, an = 0;
    for (int i = 0; i < 256; ++i) {
      unsigned x = snp[i]; snp[i] = ap; ap += x;
      x = snn[i]; snn[i] = an; an += x;
    }
    tot[0] = ap; tot[1] = an;
  }
  __syncthreads();
  float P = (float)tot[0];
  unsigned p = snp[t], f = snn[t];
  float jprev = 1.0f - (P - (float)p) / (P + (float)f);
  float contrib = 0.f;
  for (int k = 0; k < CH; ++k) {
    int b = NBINS - 1 - (j0 + k);
    unsigned ap = wsu[W_HPOS + b], an = wsu[W_HNEG + b];
    unsigned n = ap + an;
    if (n) {
      p += ap; f += an;
      float j = 1.0f - (P - (float)p) / (P + (float)f);
      contrib += (wsS[W_HSUM + b] / (float)n) * (j - jprev);
      jprev = j;
    }
  }
  red[t] = contrib;
  __syncthreads();
  for (int o = 128; o; o >>= 1) {
    if (t < o) red[t] += red[t + o];
    __syncthreads();
  }
  if (t == 0) {
    float vsum = 0.f;
    for (int n = 1; n < NC; ++n) vsum += 1.0f / (float)wsu[W_CNT + n];
    wsS[W_LOSS] = red[0] + wsS[W_SVAR] * vsum / (float)NI;
  }
}

// ---------------- Final: mean over batch
__global__ void final_kernel(const float* __restrict__ ws, float* __restrict__ out) {
  float a = 0.f;
  for (int s = 0; s < BNUM; ++s) a += ws[(size_t)s * W_STRIDE + W_LOSS];
  out[0] = 0.25f * a;
}

extern "C" void kernel_launch(void* const* d_in, const int* in_sizes, int n_in,
                              void* d_out, int out_size, void* d_ws, size_t ws_size,
                              hipStream_t stream) {
  const float* emb = (const float*)d_in[0];   // [4,2,512,512]
  const float* sig = (const float*)d_in[1];   // [4,1,512,512]
  const int*   gt  = (const int*)d_in[2];     // [4,1,512,512]
  float* out = (float*)d_out;
  float* ws  = (float*)d_ws;

  hipMemsetAsync(d_ws, 0, (size_t)BNUM * W_STRIDE * sizeof(float), stream);

  dim3 gA(256, BNUM);
  stats_kernel<<<gA, 256, 0, stream>>>(emb, sig, gt, ws);
  prep_kernel<<<BNUM, 64, 0, stream>>>(ws);
  dim3 gB(64, BNUM);
  hist_kernel<<<gB, 512, 0, stream>>>(emb, sig, gt, ws);
  scan_kernel<<<BNUM, 256, 0, stream>>>(ws);
  final_kernel<<<1, 1, 0, stream>>>(ws, out);
}

// Round 2
// 140.951 us; speedup vs baseline: 2.0490x; 2.0490x over previous
//
#include <hip/hip_runtime.h>

#define HW    262144      // 512*512
#define BNUM  4
#define NC    33          // labels 0..32
#define NI    32          // instance channels

#define NB     2048       // t-space bins
#define TMAX   16.0f
#define BSCALE 128.0f     // NB / TMAX
#define EG     8192       // e-grid bins in scan
#define ESCALE 4096.0f    // EG / 2.0

// word (float/u32) offsets within each sample's workspace slice
#define W_TH   0                    // u64[NB] packed (pos<<32)|neg -> 4096 words
#define W_E0   4096
#define W_E1   (W_E0 + NC)
#define W_SS   (W_E1 + NC)
#define W_CNT  (W_SS + NC)
#define W_SVAR (W_CNT + NC)
#define W_SIG  (W_SVAR + 1)
#define W_Q    (W_SIG + NC)
#define W_C0   (W_Q + NC)
#define W_C1   (W_C0 + NC)
#define W_LOSS (W_C1 + NC)
#define W_STRIDE 4368               // even, 16B-aligned stride

// ---------------- Pass A: per-instance stats, per-wave privatized
__global__ void __launch_bounds__(256) stats_kernel(
    const float* __restrict__ emb, const float* __restrict__ sig,
    const int* __restrict__ gt, float* __restrict__ ws) {
  int s = blockIdx.y;
  float* wsS = ws + (size_t)s * W_STRIDE;
  __shared__ float a0[4][NC], a1[4][NC], as_[4][NC];
  __shared__ unsigned ac[4][NC];
  int t = threadIdx.x;
  int w = t >> 6;
  for (int k = t; k < 4 * NC; k += 256) {
    ((float*)a0)[k] = 0.f; ((float*)a1)[k] = 0.f; ((float*)as_)[k] = 0.f;
    ((unsigned*)ac)[k] = 0u;
  }
  __syncthreads();
  const float* e0p = emb + (size_t)s * 2 * HW;
  const float* e1p = e0p + HW;
  const float* sp  = sig + (size_t)s * HW;
  const int*   gp  = gt  + (size_t)s * HW;
  int base = blockIdx.x * 1024;
  #pragma unroll
  for (int i = 0; i < 2; ++i) {
    int idx = base + i * 512 + t * 2;
    int2  lb = *(const int2*)(gp + idx);
    float2 x = *(const float2*)(e0p + idx);
    float2 y = *(const float2*)(e1p + idx);
    float2 sg = *(const float2*)(sp + idx);
    if (lb.x > 0) {
      atomicAdd(&a0[w][lb.x], x.x); atomicAdd(&a1[w][lb.x], y.x);
      atomicAdd(&as_[w][lb.x], sg.x); atomicAdd(&ac[w][lb.x], 1u);
    }
    if (lb.y > 0) {
      atomicAdd(&a0[w][lb.y], x.y); atomicAdd(&a1[w][lb.y], y.y);
      atomicAdd(&as_[w][lb.y], sg.y); atomicAdd(&ac[w][lb.y], 1u);
    }
  }
  __syncthreads();
  if (t >= 1 && t < NC) {
    float s0 = a0[0][t] + a0[1][t] + a0[2][t] + a0[3][t];
    float s1 = a1[0][t] + a1[1][t] + a1[2][t] + a1[3][t];
    float ss = as_[0][t] + as_[1][t] + as_[2][t] + as_[3][t];
    unsigned c = ac[0][t] + ac[1][t] + ac[2][t] + ac[3][t];
    if (c) {
      atomicAdd(&wsS[W_E0 + t], s0);
      atomicAdd(&wsS[W_E1 + t], s1);
      atomicAdd(&wsS[W_SS + t], ss);
      atomicAdd((unsigned*)wsS + (W_CNT + t), c);
    }
  }
}

// ---------------- Prep: centers, sigma, q = +0.5/sigma^2
__global__ void prep_kernel(float* __restrict__ ws) {
  int s = blockIdx.x;
  float* wsS = ws + (size_t)s * W_STRIDE;
  const unsigned* wsu = (const unsigned*)wsS;
  int n = threadIdx.x;
  if (n >= 1 && n < NC) {
    float inv = 1.0f / (float)wsu[W_CNT + n];
    float sg = wsS[W_SS + n] * inv;
    wsS[W_SIG + n] = sg;
    wsS[W_Q + n]   = 0.5f / (sg * sg);
    wsS[W_C0 + n]  = wsS[W_E0 + n] * inv;
    wsS[W_C1 + n]  = wsS[W_E1 + n] * inv;
  }
}

// ---------------- Pass B: t-space histogram, packed (pos<<16)|neg, 4 replicas
__global__ void __launch_bounds__(512) hist_kernel(
    const float* __restrict__ emb, const float* __restrict__ sig,
    const int* __restrict__ gt, float* __restrict__ ws) {
  int s = blockIdx.y;
  float* wsS = ws + (size_t)s * W_STRIDE;
  __shared__ unsigned hist[NB * 4];
  __shared__ float c0s[NC], c1s[NC], qs[NC], sgs[NC];
  __shared__ float vred[8];
  int t = threadIdx.x;
  int r = t & 3;
  for (int k = t; k < NB * 4; k += 512) hist[k] = 0u;
  if (t < NC) {
    c0s[t] = wsS[W_C0 + t]; c1s[t] = wsS[W_C1 + t];
    qs[t]  = wsS[W_Q + t];  sgs[t] = wsS[W_SIG + t];
  }
  __syncthreads();
  const float* e0p = emb + (size_t)s * 2 * HW;
  const float* e1p = e0p + HW;
  const float* sp  = sig + (size_t)s * HW;
  const int*   gp  = gt  + (size_t)s * HW;
  int idx = blockIdx.x * 1024 + t * 2;
  int2   lb = *(const int2*)(gp + idx);
  float2 px = *(const float2*)(e0p + idx);
  float2 py = *(const float2*)(e1p + idx);
  float2 sg = *(const float2*)(sp + idx);
  float vs = 0.f;
  if (lb.x > 0) { float d = sg.x - sgs[lb.x]; vs += d * d; }
  if (lb.y > 0) { float d = sg.y - sgs[lb.y]; vs += d * d; }
  #pragma unroll 4
  for (int n = 1; n <= NI; ++n) {
    float c0 = c0s[n], c1 = c1s[n], q = qs[n];
    // pixel 0
    {
      float dx = c0 - px.x, dy = c1 - py.x;
      float tt = (dx * dx + dy * dy) * q;
      bool pos = (lb.x == n);
      if (pos || tt < TMAX) {
        int b = (int)(tt * BSCALE); if (b > NB - 1) b = NB - 1;
        atomicAdd(&hist[(b << 2) | r], pos ? 0x10000u : 1u);
      }
    }
    // pixel 1
    {
      float dx = c0 - px.y, dy = c1 - py.y;
      float tt = (dx * dx + dy * dy) * q;
      bool pos = (lb.y == n);
      if (pos || tt < TMAX) {
        int b = (int)(tt * BSCALE); if (b > NB - 1) b = NB - 1;
        atomicAdd(&hist[(b << 2) | r], pos ? 0x10000u : 1u);
      }
    }
  }
  // variance partial reduction
  for (int o = 32; o; o >>= 1) vs += __shfl_down(vs, o);
  if ((t & 63) == 0) vred[t >> 6] = vs;
  __syncthreads();
  if (t == 0) {
    float tot = 0.f;
    for (int i = 0; i < 8; ++i) tot += vred[i];
    atomicAdd(&wsS[W_SVAR], tot);
  }
  // flush: one u64 atomic per nonzero bin
  unsigned long long* th = (unsigned long long*)wsS;  // W_TH == 0
  for (int k = t; k < NB; k += 512) {
    unsigned v = hist[k * 4] + hist[k * 4 + 1] + hist[k * 4 + 2] + hist[k * 4 + 3];
    if (v) {
      unsigned long long add = ((unsigned long long)(v >> 16) << 32) | (v & 0xFFFFu);
      atomicAdd(&th[k], add);
    }
  }
}

// ---------------- Pass C: resample to e-grid, descending Jaccard scan
__global__ void __launch_bounds__(512) scan_kernel(float* __restrict__ ws) {
  int s = blockIdx.x;
  float* wsS = ws + (size_t)s * W_STRIDE;
  const unsigned long long* th = (const unsigned long long*)wsS;
  const unsigned* wsu = (const unsigned*)wsS;
  __shared__ unsigned ep[EG], en[EG];
  __shared__ unsigned snp[512], snn[512];
  __shared__ unsigned tot[2];
  __shared__ float red[512];
  int t = threadIdx.x;
  for (int k = t; k < EG; k += 512) { ep[k] = 0u; en[k] = 0u; }
  __syncthreads();
  // scatter t-bins onto e-grid
  for (int b = t; b < NB; b += 512) {
    unsigned long long v = th[b];
    unsigned pos = (unsigned)(v >> 32), neg = (unsigned)(v & 0xFFFFFFFFu);
    if (pos | neg) {
      float tc = ((float)b + 0.5f) * (1.0f / BSCALE);
      float ex = __expf(-tc);
      if (pos) {
        float e = 2.0f - 2.0f * ex;
        int k = (int)(e * ESCALE); if (k > EG - 1) k = EG - 1;
        atomicAdd(&ep[k], pos);
      }
      if (neg) {
        float e = 2.0f * ex;
        int k = (int)(e * ESCALE); if (k > EG - 1) k = EG - 1;
        atomicAdd(&en[k], neg);
      }
    }
  }
  __syncthreads();
  // per-thread chunk sums over descending-e order
  const int CH = EG / 512;  // 16
  int j0 = t * CH;
  unsigned np = 0, nn = 0;
  for (int k = 0; k < CH; ++k) {
    int b = EG - 1 - (j0 + k);
    np += ep[b]; nn += en[b];
  }
  snp[t] = np; snn[t] = nn;
  __syncthreads();
  if (t == 0) {
    unsigned ap = 0, an = 0;
    for (int i = 0; i < 512; ++i) {
      unsigned x = snp[i]; snp[i] = ap; ap += x;
      x = snn[i]; snn[i] = an; an += x;
    }
    tot[0] = ap; tot[1] = an;
  }
  __syncthreads();
  float P = (float)tot[0];
  unsigned p = snp[t], f = snn[t];
  float jprev = 1.0f - (P - (float)p) / (P + (float)f);
  float contrib = 0.f;
  for (int k = 0; k < CH; ++k) {
    int b = EG - 1 - (j0 + k);
    unsigned ap_ = ep[b], an_ = en[b];
    if (ap_ | an_) {
      p += ap_; f += an_;
      float j = 1.0f - (P - (float)p) / (P + (float)f);
      float e = ((float)b + 0.5f) * (2.0f / EG);
      contrib += e * (j - jprev);
      jprev = j;
    }
  }
  red[t] = contrib;
  __syncthreads();
  for (int o = 256; o; o >>= 1) {
    if (t < o) red[t] += red[t + o];
    __syncthreads();
  }
  if (t == 0) {
    float vsum = 0.f;
    for (int n = 1; n < NC; ++n) vsum += 1.0f / (float)wsu[W_CNT + n];
    wsS[W_LOSS] = red[0] + wsS[W_SVAR] * vsum / (float)NI;
  }
}

// ---------------- Final: mean over batch
__global__ void final_kernel(const float* __restrict__ ws, float* __restrict__ out) {
  float a = 0.f;
  for (int s = 0; s < BNUM; ++s) a += ws[(size_t)s * W_STRIDE + W_LOSS];
  out[0] = 0.25f * a;
}

extern "C" void kernel_launch(void* const* d_in, const int* in_sizes, int n_in,
                              void* d_out, int out_size, void* d_ws, size_t ws_size,
                              hipStream_t stream) {
  const float* emb = (const float*)d_in[0];   // [4,2,512,512]
  const float* sig = (const float*)d_in[1];   // [4,1,512,512]
  const int*   gt  = (const int*)d_in[2];     // [4,1,512,512]
  float* out = (float*)d_out;
  float* ws  = (float*)d_ws;

  hipMemsetAsync(d_ws, 0, (size_t)BNUM * W_STRIDE * sizeof(float), stream);

  dim3 gA(256, BNUM);
  stats_kernel<<<gA, 256, 0, stream>>>(emb, sig, gt, ws);
  prep_kernel<<<BNUM, 64, 0, stream>>>(ws);
  dim3 gB(256, BNUM);
  hist_kernel<<<gB, 512, 0, stream>>>(emb, sig, gt, ws);
  scan_kernel<<<BNUM, 512, 0, stream>>>(ws);
  final_kernel<<<1, 1, 0, stream>>>(ws, out);
}

// Round 4
// 133.913 us; speedup vs baseline: 2.1567x; 1.0526x over previous
//
#include <hip/hip_runtime.h>

#define HW    262144      // 512*512
#define BNUM  4
#define NC    33          // labels 0..32
#define NI    32          // instance channels

#define NB     2048       // t-space bins
#define TMAX   16.0f
#define BSCALE 128.0f     // NB / TMAX
#define EG     8192       // e-grid bins in scan
#define ESCALE 4096.0f    // EG / 2.0

typedef unsigned long long ull;

// word (float/u32) offsets within each sample's workspace slice
#define W_TH   0                    // u64[NB] packed (pos<<32)|neg -> 4096 words
#define W_E0   4096
#define W_E1   (W_E0 + NC)          // 4129
#define W_SS   (W_E1 + NC)          // 4162
#define W_SS2  (W_SS + NC)          // 4195
#define W_CNT  (W_SS2 + NC)         // 4228
#define W_LOSS (W_CNT + NC)         // 4261
#define W_STRIDE 4272               // 16B-aligned stride

// ---------------- Pass A: per-instance stats, per-wave privatized
__global__ void __launch_bounds__(256) stats_kernel(
    const float* __restrict__ emb, const float* __restrict__ sig,
    const int* __restrict__ gt, float* __restrict__ ws) {
  int s = blockIdx.y;
  float* wsS = ws + (size_t)s * W_STRIDE;
  __shared__ float a0[4][NC], a1[4][NC], as_[4][NC], as2[4][NC];
  __shared__ unsigned ac[4][NC];
  int t = threadIdx.x;
  int w = t >> 6;
  for (int k = t; k < 4 * NC; k += 256) {
    ((float*)a0)[k] = 0.f; ((float*)a1)[k] = 0.f;
    ((float*)as_)[k] = 0.f; ((float*)as2)[k] = 0.f;
    ((unsigned*)ac)[k] = 0u;
  }
  __syncthreads();
  const float* e0p = emb + (size_t)s * 2 * HW;
  const float* e1p = e0p + HW;
  const float* sp  = sig + (size_t)s * HW;
  const int*   gp  = gt  + (size_t)s * HW;
  int base = blockIdx.x * 1024;
  #pragma unroll
  for (int i = 0; i < 2; ++i) {
    int idx = base + i * 512 + t * 2;
    int2  lb = *(const int2*)(gp + idx);
    float2 x = *(const float2*)(e0p + idx);
    float2 y = *(const float2*)(e1p + idx);
    float2 sg = *(const float2*)(sp + idx);
    if (lb.x > 0) {
      atomicAdd(&a0[w][lb.x], x.x); atomicAdd(&a1[w][lb.x], y.x);
      atomicAdd(&as_[w][lb.x], sg.x); atomicAdd(&as2[w][lb.x], sg.x * sg.x);
      atomicAdd(&ac[w][lb.x], 1u);
    }
    if (lb.y > 0) {
      atomicAdd(&a0[w][lb.y], x.y); atomicAdd(&a1[w][lb.y], y.y);
      atomicAdd(&as_[w][lb.y], sg.y); atomicAdd(&as2[w][lb.y], sg.y * sg.y);
      atomicAdd(&ac[w][lb.y], 1u);
    }
  }
  __syncthreads();
  if (t >= 1 && t < NC) {
    float s0 = a0[0][t] + a0[1][t] + a0[2][t] + a0[3][t];
    float s1 = a1[0][t] + a1[1][t] + a1[2][t] + a1[3][t];
    float ss = as_[0][t] + as_[1][t] + as_[2][t] + as_[3][t];
    float s2 = as2[0][t] + as2[1][t] + as2[2][t] + as2[3][t];
    unsigned c = ac[0][t] + ac[1][t] + ac[2][t] + ac[3][t];
    if (c) {
      atomicAdd(&wsS[W_E0 + t], s0);
      atomicAdd(&wsS[W_E1 + t], s1);
      atomicAdd(&wsS[W_SS + t], ss);
      atomicAdd(&wsS[W_SS2 + t], s2);
      atomicAdd((unsigned*)wsS + (W_CNT + t), c);
    }
  }
}

// ---------------- Pass B: t-space histogram, packed (pos<<16)|neg, 4 replicas
// Per-block prep of centers/q from raw stats (prep kernel eliminated).
__global__ void __launch_bounds__(512) hist_kernel(
    const float* __restrict__ emb, const int* __restrict__ gt,
    float* __restrict__ ws) {
  int s = blockIdx.y;
  float* wsS = ws + (size_t)s * W_STRIDE;
  __shared__ unsigned hist[NB * 4];
  __shared__ float c0s[NC], c1s[NC], qs[NC];
  int t = threadIdx.x;
  int r = t & 3;
  for (int k = t; k < NB * 4; k += 512) hist[k] = 0u;
  if (t >= 1 && t < NC) {
    float inv = 1.0f / (float)((const unsigned*)wsS)[W_CNT + t];
    c0s[t] = wsS[W_E0 + t] * inv;
    c1s[t] = wsS[W_E1 + t] * inv;
    float sg = wsS[W_SS + t] * inv;
    qs[t] = 0.5f / (sg * sg);
  }
  __syncthreads();
  const float* e0p = emb + (size_t)s * 2 * HW;
  const float* e1p = e0p + HW;
  const int*   gp  = gt  + (size_t)s * HW;
  int idx = blockIdx.x * 1024 + t * 2;
  int2   lb = *(const int2*)(gp + idx);
  float2 px = *(const float2*)(e0p + idx);
  float2 py = *(const float2*)(e1p + idx);
  #pragma unroll 4
  for (int n = 1; n <= NI; ++n) {
    float c0 = c0s[n], c1 = c1s[n], q = qs[n];
    {
      float dx = c0 - px.x, dy = c1 - py.x;
      float tt = (dx * dx + dy * dy) * q;
      bool pos = (lb.x == n);
      if (pos || tt < TMAX) {
        int b = (int)(tt * BSCALE); if (b > NB - 1) b = NB - 1;
        atomicAdd(&hist[(b << 2) | r], pos ? 0x10000u : 1u);
      }
    }
    {
      float dx = c0 - px.y, dy = c1 - py.y;
      float tt = (dx * dx + dy * dy) * q;
      bool pos = (lb.y == n);
      if (pos || tt < TMAX) {
        int b = (int)(tt * BSCALE); if (b > NB - 1) b = NB - 1;
        atomicAdd(&hist[(b << 2) | r], pos ? 0x10000u : 1u);
      }
    }
  }
  __syncthreads();
  // flush: one u64 atomic per nonzero bin
  ull* th = (ull*)wsS;  // W_TH == 0
  for (int k = t; k < NB; k += 512) {
    unsigned v = hist[k * 4] + hist[k * 4 + 1] + hist[k * 4 + 2] + hist[k * 4 + 3];
    if (v) {
      ull add = ((ull)(v >> 16) << 32) | (v & 0xFFFFu);
      atomicAdd(&th[k], add);
    }
  }
}

// ---------------- Pass C: resample to e-grid, PARALLEL descending Jaccard scan
__global__ void __launch_bounds__(512) scan_kernel(float* __restrict__ ws) {
  int s = blockIdx.x;
  float* wsS = ws + (size_t)s * W_STRIDE;
  const ull* th = (const ull*)wsS;
  const unsigned* wsu = (const unsigned*)wsS;
  __shared__ unsigned ep[EG], en[EG];
  __shared__ ull wsum[8];
  __shared__ float red[8];
  __shared__ float vart_s;
  int t = threadIdx.x;
  int lane = t & 63, wid = t >> 6;
  for (int k = t; k < EG; k += 512) { ep[k] = 0u; en[k] = 0u; }
  // variance term per reference: var_sigmas = POOLED S_total / c_n (scalar sum
  // over all instances, broadcast-divided), so mean over n:
  //   vart = S_total * (sum_n 1/c_n) / NI,  S_total = sum_n (SS2_n - c_n*mean_n^2)
  if (wid == 0) {
    float S = 0.f, rc = 0.f;
    if (lane >= 1 && lane < NC) {
      float c = (float)wsu[W_CNT + lane];
      float sg = wsS[W_SS + lane] / c;
      S = wsS[W_SS2 + lane] - c * sg * sg;
      rc = 1.0f / c;
    }
    for (int o = 32; o; o >>= 1) {
      S  += __shfl_down(S, o);
      rc += __shfl_down(rc, o);
    }
    if (lane == 0) vart_s = S * rc / (float)NI;
  }
  __syncthreads();
  // scatter t-bins onto e-grid
  for (int b = t; b < NB; b += 512) {
    ull v = th[b];
    unsigned pos = (unsigned)(v >> 32), neg = (unsigned)(v & 0xFFFFFFFFu);
    if (pos | neg) {
      float tc = ((float)b + 0.5f) * (1.0f / BSCALE);
      float ex = __expf(-tc);
      if (pos) {
        float e = 2.0f - 2.0f * ex;
        int k = (int)(e * ESCALE); if (k > EG - 1) k = EG - 1;
        atomicAdd(&ep[k], pos);
      }
      if (neg) {
        float e = 2.0f * ex;
        int k = (int)(e * ESCALE); if (k > EG - 1) k = EG - 1;
        atomicAdd(&en[k], neg);
      }
    }
  }
  __syncthreads();
  // per-thread chunk sums over descending-e order
  const int CH = EG / 512;  // 16
  int j0 = t * CH;
  unsigned np = 0, nn = 0;
  for (int k = 0; k < CH; ++k) {
    int b = EG - 1 - (j0 + k);
    np += ep[b]; nn += en[b];
  }
  // parallel exclusive scan of packed (np<<32)|nn across 512 threads
  ull v = ((ull)np << 32) | (ull)nn;
  ull inc = v;
  for (int o = 1; o < 64; o <<= 1) {
    ull u = __shfl_up(inc, o);
    if (lane >= o) inc += u;
  }
  if (lane == 63) wsum[wid] = inc;
  __syncthreads();
  ull offset = 0, total = 0;
  for (int i = 0; i < 8; ++i) {
    ull x = wsum[i];
    if (i < wid) offset += x;
    total += x;
  }
  ull excl = offset + inc - v;
  float P = (float)(unsigned)(total >> 32);
  unsigned p = (unsigned)(excl >> 32), f = (unsigned)(excl & 0xFFFFFFFFu);
  float jprev = 1.0f - (P - (float)p) / (P + (float)f);
  float contrib = 0.f;
  for (int k = 0; k < CH; ++k) {
    int b = EG - 1 - (j0 + k);
    unsigned ap_ = ep[b], an_ = en[b];
    if (ap_ | an_) {
      p += ap_; f += an_;
      float j = 1.0f - (P - (float)p) / (P + (float)f);
      float e = ((float)b + 0.5f) * (2.0f / EG);
      contrib += e * (j - jprev);
      jprev = j;
    }
  }
  for (int o = 32; o; o >>= 1) contrib += __shfl_down(contrib, o);
  if (lane == 0) red[wid] = contrib;
  __syncthreads();
  if (t == 0) {
    float tot = 0.f;
    for (int i = 0; i < 8; ++i) tot += red[i];
    wsS[W_LOSS] = tot + vart_s;
  }
}

// ---------------- Final: mean over batch
__global__ void final_kernel(const float* __restrict__ ws, float* __restrict__ out) {
  float a = 0.f;
  for (int s = 0; s < BNUM; ++s) a += ws[(size_t)s * W_STRIDE + W_LOSS];
  out[0] = 0.25f * a;
}

extern "C" void kernel_launch(void* const* d_in, const int* in_sizes, int n_in,
                              void* d_out, int out_size, void* d_ws, size_t ws_size,
                              hipStream_t stream) {
  const float* emb = (const float*)d_in[0];   // [4,2,512,512]
  const float* sig = (const float*)d_in[1];   // [4,1,512,512]
  const int*   gt  = (const int*)d_in[2];     // [4,1,512,512]
  float* out = (float*)d_out;
  float* ws  = (float*)d_ws;

  hipMemsetAsync(d_ws, 0, (size_t)BNUM * W_STRIDE * sizeof(float), stream);

  dim3 gA(256, BNUM);
  stats_kernel<<<gA, 256, 0, stream>>>(emb, sig, gt, ws);
  dim3 gB(256, BNUM);
  hist_kernel<<<gB, 512, 0, stream>>>(emb, gt, ws);
  scan_kernel<<<BNUM, 512, 0, stream>>>(ws);
  final_kernel<<<1, 1, 0, stream>>>(ws, out);
}